// Round 5
// baseline (125.172 us; speedup 1.0000x reference)
//
#include <hip/hip_runtime.h>

#define LSEQ 384
#define EMBED 1280
#define HID 256
#define NBINS 10
#define GM 768          // B*L rows
#define KP 512          // packed K: 2 signs x HID

typedef __attribute__((ext_vector_type(8))) short short8;
typedef __attribute__((ext_vector_type(4))) short short4v;
typedef __attribute__((ext_vector_type(4))) float float4v;
typedef __attribute__((ext_vector_type(2))) float float2v;

__device__ __forceinline__ unsigned bfbits(float f) {
    unsigned u = __builtin_bit_cast(unsigned, f);
    return (u + 0x7fffu + ((u >> 16) & 1u)) >> 16;   // RNE
}
__device__ __forceinline__ short f2bf(float f) { return (short)bfbits(f); }

// ---------------- P: xb = bf16(x) [768][1280]; WT = bf16([Wi|Wj]^T) [512][1280]
__global__ __launch_bounds__(256) void k_prep(
    const float* __restrict__ x, const float* __restrict__ Wi, const float* __restrict__ Wj,
    short* __restrict__ xb, short* __restrict__ WT)
{
    __shared__ float tile[32][33];
    const int t = threadIdx.x;
    int bx = blockIdx.x;
    if (bx < 480) {
        const int idx = bx * 256 + t;
        const float4v a = ((const float4v*)x)[idx * 2];
        const float4v b = ((const float4v*)x)[idx * 2 + 1];
        short8 o;
        o[0] = f2bf(a.x); o[1] = f2bf(a.y); o[2] = f2bf(a.z); o[3] = f2bf(a.w);
        o[4] = f2bf(b.x); o[5] = f2bf(b.y); o[6] = f2bf(b.z); o[7] = f2bf(b.w);
        ((short8*)xb)[idx] = o;
    } else {
        bx -= 480;
        const int isJ = bx >= 320 ? 1 : 0;
        if (isJ) bx -= 320;
        const int tk = bx % 40, tn = bx / 40;
        const int k0 = tk * 32, n0 = tn * 32;
        const float* __restrict__ W = isJ ? Wj : Wi;
        const int r = t >> 3, c4 = (t & 7) * 4;
        const float4v v = *(const float4v*)(W + (size_t)(k0 + r) * HID + n0 + c4);
        tile[r][c4 + 0] = v.x; tile[r][c4 + 1] = v.y;
        tile[r][c4 + 2] = v.z; tile[r][c4 + 3] = v.w;
        __syncthreads();
        const int n = r, kc = c4;
        short4v o;
        o.x = f2bf(tile[kc + 0][n]); o.y = f2bf(tile[kc + 1][n]);
        o.z = f2bf(tile[kc + 2][n]); o.w = f2bf(tile[kc + 3][n]);
        *(short4v*)(WT + (size_t)(isJ * HID + n0 + n) * EMBED + k0 + kc) = o;
    }
}

// ---------------- G: C[768,512] = xb @ WT^T, bias+relu+-, fold Wo -> Aef/Bef.
// LDS-free K-loop: per wave 40x (2 global dwordx4 frag loads + 1 MFMA), no barriers.
// Epilogue bounces C tile through 4KB LDS, then coalesced 64B-run packed stores.
// grid (24,16) = 384 blocks, 4 waves (mh=w&1, nh=w>>1).
__global__ __launch_bounds__(256) void k_gemm_pack(
    const short* __restrict__ xb, const short* __restrict__ WT,
    const float* __restrict__ bi, const float* __restrict__ bj, const float* __restrict__ Wo,
    short* __restrict__ Aef, short* __restrict__ Bef)
{
    __shared__ float sC[32 * 32];        // [m][h'] 4KB
    __shared__ float woS[32 * NBINS];    // Wo rows for this h-tile (isI only)

    const int tid = threadIdx.x;
    const int lane = tid & 63, w = tid >> 6;
    const int mh = w & 1, nh = w >> 1;
    const int l15 = lane & 15, q = lane >> 4;
    const int m0 = blockIdx.x * 32, n0 = blockIdx.y * 32;
    const bool isI = (n0 < HID);

    if (isI) {  // Wo[n0..n0+32)[0..10) = 320 contiguous floats
        for (int t = tid; t < 32 * NBINS; t += 256) woS[t] = Wo[n0 * NBINS + t];
    }

    const short* ap = xb + (size_t)(m0 + mh * 16 + l15) * EMBED + q * 8;
    const short* bp = WT + (size_t)(n0 + nh * 16 + l15) * EMBED + q * 8;

    float4v acc = {0.f, 0.f, 0.f, 0.f};
#pragma unroll 8
    for (int ks = 0; ks < EMBED / 32; ++ks) {
        const short8 af = *(const short8*)(ap + ks * 32);
        const short8 bf = *(const short8*)(bp + ks * 32);
        acc = __builtin_amdgcn_mfma_f32_16x16x32_bf16(af, bf, acc, 0, 0, 0);
    }

    const int ncol = n0 + nh * 16 + l15;
    const float bv = isI ? bi[ncol] : bj[ncol - HID];
#pragma unroll
    for (int r = 0; r < 4; ++r)
        sC[(mh * 16 + q * 4 + r) * 32 + nh * 16 + l15] = acc[r] + bv;
    __syncthreads();

    // pack: thread t -> m-row (t>>3), 4 h-values ((t&7)*4 ..+4); stores are
    // 64B contiguous runs per 8 threads (dwordx2 each).
    const int mr = tid >> 3;
    const int m = m0 + mr;
    const int hq = (tid & 7) * 4;
    float v[4];
#pragma unroll
    for (int c = 0; c < 4; ++c) v[c] = sC[mr * 32 + hq + c];

    if (isI) {
        const int hbase = n0 + hq;
#pragma unroll
        for (int nb = 0; nb < NBINS; ++nb) {
            float wv[4];
#pragma unroll
            for (int c = 0; c < 4; ++c) wv[c] = woS[(hq + c) * NBINS + nb];
            unsigned dp[2], dm[2];
#pragma unroll
            for (int g = 0; g < 2; ++g) {
                const unsigned p0 = bfbits(fmaxf(v[2 * g], 0.f) * wv[2 * g]);
                const unsigned p1 = bfbits(fmaxf(v[2 * g + 1], 0.f) * wv[2 * g + 1]);
                const unsigned m0_ = bfbits(fmaxf(-v[2 * g], 0.f) * wv[2 * g]);
                const unsigned m1_ = bfbits(fmaxf(-v[2 * g + 1], 0.f) * wv[2 * g + 1]);
                dp[g] = (p1 << 16) | p0;
                dm[g] = (m1_ << 16) | m0_;
            }
            unsigned* basep = (unsigned*)(Aef + ((size_t)nb * GM + m) * KP + hbase);
            unsigned* basem = (unsigned*)(Aef + ((size_t)nb * GM + m) * KP + HID + hbase);
            basep[0] = dp[0]; basep[1] = dp[1];
            basem[0] = dm[0]; basem[1] = dm[1];
        }
    } else {
        const int hbase = (n0 - HID) + hq;
        unsigned dp[2], dm[2];
#pragma unroll
        for (int g = 0; g < 2; ++g) {
            const unsigned p0 = bfbits(fmaxf(v[2 * g], 0.f));
            const unsigned p1 = bfbits(fmaxf(v[2 * g + 1], 0.f));
            const unsigned m0_ = bfbits(fmaxf(-v[2 * g], 0.f));
            const unsigned m1_ = bfbits(fmaxf(-v[2 * g + 1], 0.f));
            dp[g] = (p1 << 16) | p0;
            dm[g] = (m1_ << 16) | m0_;
        }
        unsigned* basep = (unsigned*)(Bef + (size_t)m * KP + hbase);
        unsigned* basem = (unsigned*)(Bef + (size_t)m * KP + HID + hbase);
        basep[0] = dp[0]; basep[1] = dp[1];
        basem[0] = dm[0]; basem[1] = dm[1];
    }
}

// ---------------- K2: out[b,i,j,:] pair GEMM, K=512. LDS-free K-loop.
// grid (12,12,2) = 288 blocks, 4 waves: wave = (ih=w&1, bin-half bh=w>>1).
// Per ks: 2 B-frag + 5 A-frag dwordx4 loads, 10 MFMAs; no barriers -> compiler
// pipelines with fine-grained vmcnt. LDS used only for the output bounce.
__global__ __launch_bounds__(256) void k2_pair(
    const short* __restrict__ Aef, const short* __restrict__ Bef,
    const float* __restrict__ bo, float* __restrict__ out)
{
    __shared__ float sout[32 * 32 * NBINS];   // 40KB (epilogue only)

    const int tid = threadIdx.x;
    const int lane = tid & 63, w = tid >> 6;
    const int ih = w & 1, nb0 = (w >> 1) * 5;
    const int l15 = lane & 15, q = lane >> 4;
    const int b = blockIdx.z;
    const int i0 = blockIdx.x * 32, j0 = blockIdx.y * 32;

    const short* aBase = Aef + ((size_t)nb0 * GM + (size_t)(b * LSEQ + i0 + ih * 16 + l15)) * KP + q * 8;
    const short* bBase = Bef + (size_t)(b * LSEQ + j0 + l15) * KP + q * 8;

    float4v acc[2][5];
#pragma unroll
    for (int jh = 0; jh < 2; ++jh)
#pragma unroll
        for (int nn = 0; nn < 5; ++nn) acc[jh][nn] = (float4v){0.f, 0.f, 0.f, 0.f};

#pragma unroll 2
    for (int ks = 0; ks < KP / 32; ++ks) {
        const short8 b0 = *(const short8*)(bBase + ks * 32);
        const short8 b1 = *(const short8*)(bBase + (size_t)16 * KP + ks * 32);
#pragma unroll
        for (int nn = 0; nn < 5; ++nn) {
            const short8 af = *(const short8*)(aBase + (size_t)nn * GM * KP + ks * 32);
            acc[0][nn] = __builtin_amdgcn_mfma_f32_16x16x32_bf16(af, b0, acc[0][nn], 0, 0, 0);
            acc[1][nn] = __builtin_amdgcn_mfma_f32_16x16x32_bf16(af, b1, acc[1][nn], 0, 0, 0);
        }
    }

    float bov[NBINS];
    const float2v* bop = (const float2v*)bo;
#pragma unroll
    for (int c = 0; c < 5; ++c) { float2v tv = bop[c]; bov[2 * c] = tv.x; bov[2 * c + 1] = tv.y; }

#pragma unroll
    for (int jh = 0; jh < 2; ++jh)
#pragma unroll
        for (int nn = 0; nn < 5; ++nn)
#pragma unroll
            for (int r = 0; r < 4; ++r)
                sout[((ih * 16 + q * 4 + r) * 32 + (jh * 16 + l15)) * NBINS + nb0 + nn] =
                    acc[jh][nn][r] + bov[nb0 + nn];
    __syncthreads();

    // coalesced copy: 32 rows x 320 floats = 5120 float2, 20 per thread
    const float2v* s2 = (const float2v*)sout;
#pragma unroll
    for (int t = 0; t < 20; ++t) {
        const int f = t * 256 + tid;
        const int row = f / 160;
        const int rq = f - row * 160;
        float2v* dst = (float2v*)(out + ((size_t)(b * LSEQ + i0 + row) * LSEQ + j0) * NBINS);
        dst[rq] = s2[f];
    }
}

extern "C" void kernel_launch(void* const* d_in, const int* in_sizes, int n_in,
                              void* d_out, int out_size, void* d_ws, size_t ws_size,
                              hipStream_t stream)
{
    const float* x  = (const float*)d_in[0];
    const float* Wi = (const float*)d_in[1];
    const float* bi = (const float*)d_in[2];
    const float* Wj = (const float*)d_in[3];
    const float* bj = (const float*)d_in[4];
    const float* Wo = (const float*)d_in[5];
    const float* bo = (const float*)d_in[6];
    float* out = (float*)d_out;

    char* p = (char*)d_ws;
    short* xb  = (short*)p;                 p += (size_t)GM * EMBED * 2;      // 1.97 MB
    short* WT  = (short*)p;                 p += (size_t)KP * EMBED * 2;      // 1.31 MB
    short* Aef = (short*)p;                 p += (size_t)NBINS * GM * KP * 2; // 7.86 MB
    short* Bef = (short*)p;                                                   // 0.79 MB

    k_prep<<<1120, 256, 0, stream>>>(x, Wi, Wj, xb, WT);
    k_gemm_pack<<<dim3(GM / 32, KP / 32), 256, 0, stream>>>(xb, WT, bi, bj, Wo, Aef, Bef);
    k2_pair<<<dim3(LSEQ / 32, LSEQ / 32, 2), 256, 0, stream>>>(Aef, Bef, bo, out);
}

// Round 7
// 99.057 us; speedup vs baseline: 1.2636x; 1.2636x over previous
//
#include <hip/hip_runtime.h>

#define LSEQ 384
#define EMBED 1280
#define HID 256
#define NBINS 10
#define GM 768           // B*L rows
#define KP 512           // packed K: 2 signs x HID
#define NJN (LSEQ * NBINS)   // 3840 jn-columns per batch
#define NKX (EMBED / 32)     // 40 k-chunks, stage 1
#define NKP (KP / 32)        // 16 k-chunks, stage 2

typedef __attribute__((ext_vector_type(8))) short short8;
typedef __attribute__((ext_vector_type(4))) float float4v;

__device__ __forceinline__ unsigned bfbits(float f) {
    unsigned u = __builtin_bit_cast(unsigned, f);
    return (u + 0x7fffu + ((u >> 16) & 1u)) >> 16;   // RNE
}
__device__ __forceinline__ float bf2f(short s) {
    unsigned u = ((unsigned)(unsigned short)s) << 16;
    return __builtin_bit_cast(float, u);
}

// Fragment-major layout: chunk(rt, kc) = 1KB = [lane64][8 bf16];
// lane = (row%16) + 16*((k%32)/8); rt = row/16, kc = k/32.

// ---------------- P: xb_f frag-major [48rt][40kc]; WT_f frag-major [32rt][40kc]
__global__ __launch_bounds__(256) void k_prep(
    const float* __restrict__ x, const float* __restrict__ Wi, const float* __restrict__ Wj,
    short* __restrict__ xb_f, short* __restrict__ WT_f)
{
    __shared__ float tile[32][33];
    const int t = threadIdx.x;
    int bx = blockIdx.x;
    if (bx < 480) {                       // x -> xb_f, 4 chunks per block
        const int cid = bx * 4 + (t >> 6);
        const int rt = cid / NKX, kc = cid - rt * NKX;
        const int lane = t & 63;
        const int row = rt * 16 + (lane & 15);
        const int k = kc * 32 + (lane >> 4) * 8;
        const float4v a = *(const float4v*)(x + (size_t)row * EMBED + k);
        const float4v b = *(const float4v*)(x + (size_t)row * EMBED + k + 4);
        short8 o;
        o[0] = (short)bfbits(a.x); o[1] = (short)bfbits(a.y);
        o[2] = (short)bfbits(a.z); o[3] = (short)bfbits(a.w);
        o[4] = (short)bfbits(b.x); o[5] = (short)bfbits(b.y);
        o[6] = (short)bfbits(b.z); o[7] = (short)bfbits(b.w);
        *(short8*)(xb_f + (size_t)cid * 512 + lane * 8) = o;
    } else {                              // W transpose -> WT_f
        bx -= 480;
        const int isJ = bx >= 320 ? 1 : 0;
        if (isJ) bx -= 320;
        const int tk = bx % 40, tn = bx / 40;
        const int k0 = tk * 32, n0 = tn * 32;
        const float* __restrict__ W = isJ ? Wj : Wi;
        const int r = t >> 3, c4 = (t & 7) * 4;
        const float4v v = *(const float4v*)(W + (size_t)(k0 + r) * HID + n0 + c4);
        tile[r][c4 + 0] = v.x; tile[r][c4 + 1] = v.y;
        tile[r][c4 + 2] = v.z; tile[r][c4 + 3] = v.w;
        __syncthreads();
        const int chunkhalf = t >> 7;             // which 16-n group
        const int l = (t & 127) >> 1;             // lane in chunk
        const int hs = t & 1;                     // 8B half
        const int n_loc = chunkhalf * 16 + (l & 15);
        const int k_loc = (l >> 4) * 8 + hs * 4;
        const int rt = isJ * 16 + tn * 2 + chunkhalf;
        unsigned d0 = bfbits(tile[k_loc + 0][n_loc]) | (bfbits(tile[k_loc + 1][n_loc]) << 16);
        unsigned d1 = bfbits(tile[k_loc + 2][n_loc]) | (bfbits(tile[k_loc + 3][n_loc]) << 16);
        unsigned* dst = (unsigned*)(WT_f + ((size_t)rt * NKX + tk) * 512 + l * 8 + hs * 4);
        dst[0] = d0; dst[1] = d1;
    }
}

// ---------------- G: C[768,512] = xb @ [Wi|Wj]^T; epilogue:
//   i-half  -> A_f frag-major [48rt][16kc] = relu+-(xi)
//   j-half  -> Bj row-major [768][512] bf16 = relu+-(xj)
// LDS-free K-loop, coalesced 1KB frag loads. grid (24,16), 4-wave quadrants.
__global__ __launch_bounds__(256) void k_gemm(
    const short* __restrict__ xb_f, const short* __restrict__ WT_f,
    const float* __restrict__ bi, const float* __restrict__ bj,
    short* __restrict__ A_f, short* __restrict__ Bj)
{
    __shared__ float sC[32][33];
    const int tid = threadIdx.x;
    const int lane = tid & 63, w = tid >> 6;
    const int mh = w & 1, nh = w >> 1;
    const int l15 = lane & 15, q = lane >> 4;
    const int m0 = blockIdx.x * 32, n0 = blockIdx.y * 32;
    const bool isI = (n0 < HID);

    const short* ap = xb_f + ((size_t)(blockIdx.x * 2 + mh) * NKX) * 512 + lane * 8;
    const short* bp = WT_f + ((size_t)(blockIdx.y * 2 + nh) * NKX) * 512 + lane * 8;

    float4v acc = {0.f, 0.f, 0.f, 0.f};
#pragma unroll 5
    for (int ks = 0; ks < NKX; ++ks) {
        const short8 af = *(const short8*)(ap + ks * 512);
        const short8 bf = *(const short8*)(bp + ks * 512);
        acc = __builtin_amdgcn_mfma_f32_16x16x32_bf16(af, bf, acc, 0, 0, 0);
    }

    const int nloc = nh * 16 + l15;
    const float bv = isI ? bi[n0 + nloc] : bj[n0 - HID + nloc];
#pragma unroll
    for (int r = 0; r < 4; ++r)
        sC[mh * 16 + q * 4 + r][nloc] = acc[r] + bv;
    __syncthreads();

    if (isI) {
        // 4 chunks: (g m-group) x (sign); fully coalesced 1KB stores
        const int g = tid >> 7, sign = (tid >> 6) & 1, l = tid & 63;
        const int mr = g * 16 + (l & 15);
        const int kq = (l >> 4) * 8;
        short8 o;
#pragma unroll
        for (int c = 0; c < 8; ++c) {
            const float v = sC[mr][kq + c];
            o[c] = (short)bfbits(sign ? fmaxf(-v, 0.f) : fmaxf(v, 0.f));
        }
        const int rt = blockIdx.x * 2 + g;
        const int kc = (n0 >> 5) + sign * 8;
        *(short8*)(A_f + ((size_t)rt * NKP + kc) * 512 + l * 8) = o;
    } else {
        const int mr = tid >> 3;
        const int hq = (tid & 7) * 4;
        const int h = (n0 - HID) + hq;
        unsigned dp[2], dm[2];
#pragma unroll
        for (int g2 = 0; g2 < 2; ++g2) {
            const float v0 = sC[mr][hq + 2 * g2], v1 = sC[mr][hq + 2 * g2 + 1];
            dp[g2] = bfbits(fmaxf(v0, 0.f)) | (bfbits(fmaxf(v1, 0.f)) << 16);
            dm[g2] = bfbits(fmaxf(-v0, 0.f)) | (bfbits(fmaxf(-v1, 0.f)) << 16);
        }
        unsigned* basep = (unsigned*)(Bj + (size_t)(m0 + mr) * KP + h);
        unsigned* basem = (unsigned*)(Bj + (size_t)(m0 + mr) * KP + HID + h);
        basep[0] = dp[0]; basep[1] = dp[1];
        basem[0] = dm[0]; basem[1] = dm[1];
    }
}

// ---------------- PB: B'_f[(b*240+jt)][16kc] frag-major = Bj[j][k] * Wo[k&255][n]
// jn = jt*16 + (lane&15); j = jn/10, n = jn%10. grid (240,2).
__global__ __launch_bounds__(256) void k_pack_b(
    const short* __restrict__ Bj, const float* __restrict__ Wo, short* __restrict__ Bp_f)
{
    __shared__ float woL[HID * NBINS];    // 10KB
    __shared__ short bjL[3][KP];          // 3KB
    const int t = threadIdx.x;
    const int jt = blockIdx.x, b = blockIdx.y;
    const int j0 = (jt * 16) / NBINS;

    for (int i = t; i < HID * NBINS; i += 256) woL[i] = Wo[i];
    // 3 rows x 256 dwords = 768 dwords (BUGFIX from R6: was only loading 192)
    for (int i = t; i < 3 * 256; i += 256) {
        const int r = i >> 8, d = i & 255;
        const int jrow = j0 + r;
        const int grow = b * LSEQ + (jrow > LSEQ - 1 ? LSEQ - 1 : jrow);
        ((unsigned*)bjL[r])[d] = ((const unsigned*)(Bj + (size_t)grow * KP))[d];
    }
    __syncthreads();

    const int lane = t & 63, w = t >> 6;
    const int jn = jt * 16 + (lane & 15);
    const int j = jn / NBINS, n = jn - j * NBINS;
    const int jloc = j - j0;
    const int kq = (lane >> 4) * 8;
#pragma unroll
    for (int p = 0; p < 4; ++p) {
        const int kc = w + p * 4;
        const int kbase = kc * 32 + kq;
        short8 o;
#pragma unroll
        for (int c = 0; c < 8; ++c) {
            const int k = kbase + c;
            o[c] = (short)bfbits(bf2f(bjL[jloc][k]) * woL[(k & (HID - 1)) * NBINS + n]);
        }
        *(short8*)(Bp_f + ((size_t)(b * 240 + jt) * NKP + kc) * 512 + lane * 8) = o;
    }
}

// ---------------- K2: out[b][i][jn] = A_f(i) . B'_f(jn) + bo[n]
// GEMM M=384,N=3840,K=512 per batch. Block 64i x 64jn, 4 waves, wave=32x32 (2x2 frags).
// LDS-free, no barriers; 4 coalesced 1KB loads per 4 MFMAs per ks.
__global__ __launch_bounds__(256) void k2_pair(
    const short* __restrict__ A_f, const short* __restrict__ Bp_f,
    const float* __restrict__ bo, float* __restrict__ out)
{
    const int tid = threadIdx.x;
    const int lane = tid & 63, w = tid >> 6;
    const int iw = w & 1, jw = w >> 1;
    const int l15 = lane & 15, q = lane >> 4;
    const int b = blockIdx.z;
    const int i0 = blockIdx.x * 64, jn0 = blockIdx.y * 64;

    const short* ap = A_f + ((size_t)(b * 24 + (i0 >> 4) + iw * 2) * NKP) * 512 + lane * 8;
    const short* bp = Bp_f + ((size_t)(b * 240 + (jn0 >> 4) + jw * 2) * NKP) * 512 + lane * 8;

    float4v acc[2][2];
#pragma unroll
    for (int ia = 0; ia < 2; ++ia)
#pragma unroll
        for (int jb = 0; jb < 2; ++jb) acc[ia][jb] = (float4v){0.f, 0.f, 0.f, 0.f};

#pragma unroll 2
    for (int ks = 0; ks < NKP; ++ks) {
        const short8 af0 = *(const short8*)(ap + ks * 512);
        const short8 af1 = *(const short8*)(ap + (NKP + ks) * 512);
        const short8 bf0 = *(const short8*)(bp + ks * 512);
        const short8 bf1 = *(const short8*)(bp + (NKP + ks) * 512);
        acc[0][0] = __builtin_amdgcn_mfma_f32_16x16x32_bf16(af0, bf0, acc[0][0], 0, 0, 0);
        acc[0][1] = __builtin_amdgcn_mfma_f32_16x16x32_bf16(af0, bf1, acc[0][1], 0, 0, 0);
        acc[1][0] = __builtin_amdgcn_mfma_f32_16x16x32_bf16(af1, bf0, acc[1][0], 0, 0, 0);
        acc[1][1] = __builtin_amdgcn_mfma_f32_16x16x32_bf16(af1, bf1, acc[1][1], 0, 0, 0);
    }

    // epilogue: direct stores; C layout col=l15, row=q*4+r
#pragma unroll
    for (int jb = 0; jb < 2; ++jb) {
        const int jn = jn0 + jw * 32 + jb * 16 + l15;
        const int n = jn - (jn / NBINS) * NBINS;
        const float bv = bo[n];
#pragma unroll
        for (int ia = 0; ia < 2; ++ia) {
            const int i = i0 + iw * 32 + ia * 16 + q * 4;
            float* orow = out + ((size_t)(b * LSEQ + i) * NJN) + jn;
#pragma unroll
            for (int r = 0; r < 4; ++r)
                orow[(size_t)r * NJN] = acc[ia][jb][r] + bv;
        }
    }
}

extern "C" void kernel_launch(void* const* d_in, const int* in_sizes, int n_in,
                              void* d_out, int out_size, void* d_ws, size_t ws_size,
                              hipStream_t stream)
{
    const float* x  = (const float*)d_in[0];
    const float* Wi = (const float*)d_in[1];
    const float* bi = (const float*)d_in[2];
    const float* Wj = (const float*)d_in[3];
    const float* bj = (const float*)d_in[4];
    const float* Wo = (const float*)d_in[5];
    const float* bo = (const float*)d_in[6];
    float* out = (float*)d_out;

    char* p = (char*)d_ws;
    short* xb_f = (short*)p;  p += (size_t)48 * NKX * 512 * 2;        // 1.92 MB
    short* WT_f = (short*)p;  p += (size_t)32 * NKX * 512 * 2;        // 1.28 MB
    short* A_f  = (short*)p;  p += (size_t)48 * NKP * 512 * 2;        // 0.77 MB
    short* Bj   = (short*)p;  p += (size_t)GM * KP * 2;               // 0.77 MB
    short* Bp_f = (short*)p;                                           // 7.86 MB

    k_prep<<<1120, 256, 0, stream>>>(x, Wi, Wj, xb_f, WT_f);
    k_gemm<<<dim3(GM / 32, 512 / 32), 256, 0, stream>>>(xb_f, WT_f, bi, bj, A_f, Bj);
    k_pack_b<<<dim3(240, 2), 256, 0, stream>>>(Bj, Wo, Bp_f);
    k2_pair<<<dim3(LSEQ / 64, NJN / 64, 2), 256, 0, stream>>>(A_f, Bp_f, bo, out);
}

// Round 8
// 95.240 us; speedup vs baseline: 1.3143x; 1.0401x over previous
//
#include <hip/hip_runtime.h>

#define LSEQ 384
#define EMBED 1280
#define HID 256
#define NBINS 10
#define GM 768           // B*L rows
#define KP 512           // packed K: 2 signs x HID
#define NJN (LSEQ * NBINS)   // 3840 jn-columns per batch
#define NKX (EMBED / 32)     // 40 k-chunks, stage 1
#define NKP (KP / 32)        // 16 k-chunks, stage 2

typedef __attribute__((ext_vector_type(8))) short short8;
typedef __attribute__((ext_vector_type(4))) float float4v;

__device__ __forceinline__ unsigned bfbits(float f) {
    unsigned u = __builtin_bit_cast(unsigned, f);
    return (u + 0x7fffu + ((u >> 16) & 1u)) >> 16;   // RNE
}

// Fragment-major layout: chunk(rt, kc) = 1KB = [lane64][8 bf16];
// lane = (row%16) + 16*((k%32)/8); rt = row/16, kc = k/32.

// ---------------- P: xb_f frag-major [48rt][40kc]; WT_f frag-major [32rt][40kc]
__global__ __launch_bounds__(256) void k_prep(
    const float* __restrict__ x, const float* __restrict__ Wi, const float* __restrict__ Wj,
    short* __restrict__ xb_f, short* __restrict__ WT_f)
{
    __shared__ float tile[32][33];
    const int t = threadIdx.x;
    int bx = blockIdx.x;
    if (bx < 480) {                       // x -> xb_f, 4 chunks per block
        const int cid = bx * 4 + (t >> 6);
        const int rt = cid / NKX, kc = cid - rt * NKX;
        const int lane = t & 63;
        const int row = rt * 16 + (lane & 15);
        const int k = kc * 32 + (lane >> 4) * 8;
        const float4v a = *(const float4v*)(x + (size_t)row * EMBED + k);
        const float4v b = *(const float4v*)(x + (size_t)row * EMBED + k + 4);
        short8 o;
        o[0] = (short)bfbits(a.x); o[1] = (short)bfbits(a.y);
        o[2] = (short)bfbits(a.z); o[3] = (short)bfbits(a.w);
        o[4] = (short)bfbits(b.x); o[5] = (short)bfbits(b.y);
        o[6] = (short)bfbits(b.z); o[7] = (short)bfbits(b.w);
        *(short8*)(xb_f + (size_t)cid * 512 + lane * 8) = o;
    } else {                              // W transpose -> WT_f
        bx -= 480;
        const int isJ = bx >= 320 ? 1 : 0;
        if (isJ) bx -= 320;
        const int tk = bx % 40, tn = bx / 40;
        const int k0 = tk * 32, n0 = tn * 32;
        const float* __restrict__ W = isJ ? Wj : Wi;
        const int r = t >> 3, c4 = (t & 7) * 4;
        const float4v v = *(const float4v*)(W + (size_t)(k0 + r) * HID + n0 + c4);
        tile[r][c4 + 0] = v.x; tile[r][c4 + 1] = v.y;
        tile[r][c4 + 2] = v.z; tile[r][c4 + 3] = v.w;
        __syncthreads();
        const int chunkhalf = t >> 7;             // which 16-n group
        const int l = (t & 127) >> 1;             // lane in chunk
        const int hs = t & 1;                     // 8B half
        const int n_loc = chunkhalf * 16 + (l & 15);
        const int k_loc = (l >> 4) * 8 + hs * 4;
        const int rt = isJ * 16 + tn * 2 + chunkhalf;
        unsigned d0 = bfbits(tile[k_loc + 0][n_loc]) | (bfbits(tile[k_loc + 1][n_loc]) << 16);
        unsigned d1 = bfbits(tile[k_loc + 2][n_loc]) | (bfbits(tile[k_loc + 3][n_loc]) << 16);
        unsigned* dst = (unsigned*)(WT_f + ((size_t)rt * NKX + tk) * 512 + l * 8 + hs * 4);
        dst[0] = d0; dst[1] = d1;
    }
}

// ---------------- G: C[768,512] = xb @ [Wi|Wj]^T; fused epilogues:
//   i-half (n0<256) -> A_f frag-major [48rt][16kc] = relu+-(xi)
//   j-half          -> Bp_f frag-major directly: relu+-(xj)[j][h] * Wo[h][n]
// LDS-free K-loop, coalesced 1KB frag loads. grid (24,16), 4-wave quadrants.
__global__ __launch_bounds__(256) void k_gemm_pack(
    const short* __restrict__ xb_f, const short* __restrict__ WT_f,
    const float* __restrict__ bi, const float* __restrict__ bj, const float* __restrict__ Wo,
    short* __restrict__ A_f, short* __restrict__ Bp_f)
{
    __shared__ float sC[32][33];
    __shared__ float woS[32 * NBINS];
    const int tid = threadIdx.x;
    const int lane = tid & 63, w = tid >> 6;
    const int mh = w & 1, nh = w >> 1;
    const int l15 = lane & 15, q = lane >> 4;
    const int m0 = blockIdx.x * 32, n0 = blockIdx.y * 32;
    const bool isI = (n0 < HID);

    if (!isI) {   // Wo rows h0..h0+32 = 320 contiguous floats
        for (int i = tid; i < 32 * NBINS; i += 256) woS[i] = Wo[(n0 - HID) * NBINS + i];
    }

    const short* ap = xb_f + ((size_t)(blockIdx.x * 2 + mh) * NKX) * 512 + lane * 8;
    const short* bp = WT_f + ((size_t)(blockIdx.y * 2 + nh) * NKX) * 512 + lane * 8;

    float4v acc = {0.f, 0.f, 0.f, 0.f};
#pragma unroll 5
    for (int ks = 0; ks < NKX; ++ks) {
        const short8 af = *(const short8*)(ap + ks * 512);
        const short8 bf = *(const short8*)(bp + ks * 512);
        acc = __builtin_amdgcn_mfma_f32_16x16x32_bf16(af, bf, acc, 0, 0, 0);
    }

    const int nloc = nh * 16 + l15;
    const float bv = isI ? bi[n0 + nloc] : bj[n0 - HID + nloc];
#pragma unroll
    for (int r = 0; r < 4; ++r)
        sC[mh * 16 + q * 4 + r][nloc] = acc[r] + bv;
    __syncthreads();

    if (isI) {
        // 4 chunks: (g m-group) x (sign); fully coalesced 1KB stores
        const int g = tid >> 7, sign = (tid >> 6) & 1, l = tid & 63;
        const int mr = g * 16 + (l & 15);
        const int kq = (l >> 4) * 8;
        short8 o;
#pragma unroll
        for (int c = 0; c < 8; ++c) {
            const float v = sC[mr][kq + c];
            o[c] = (short)bfbits(sign ? fmaxf(-v, 0.f) : fmaxf(v, 0.f));
        }
        const int rt = blockIdx.x * 2 + g;
        const int kc = (n0 >> 5) + sign * 8;
        *(short8*)(A_f + ((size_t)rt * NKP + kc) * 512 + l * 8) = o;
    } else {
        // Bp_f pack: 40 chunks = 20 jn-rts x 2 signs, 1KB coalesced stores.
        const int h0 = n0 - HID;
        const int bb = m0 >= LSEQ ? 1 : 0;
        const int jloc0 = m0 - bb * LSEQ;          // j-tile base within batch
        const int rt0 = (jloc0 * NBINS) >> 4;      // exact: 32 | jloc0
        const int l = tid & 63;
        const int c0 = tid >> 6;                   // 0..3
        const int ll15 = l & 15, e8 = (l >> 4) * 8;
#pragma unroll
        for (int s = 0; s < 10; ++s) {
            const int c = s * 4 + c0;              // 0..39
            const int sgn = c & 1, rtl = c >> 1;
            const int jn = (rt0 + rtl) * 16 + ll15;
            const int j = (jn * 6554) >> 16;       // jn/10 for jn<16384
            const int n = jn - j * NBINS;
            const int jl = j - jloc0;              // 0..31
            short8 o;
#pragma unroll
            for (int e = 0; e < 8; ++e) {
                const int hc = e8 + e;
                const float v = sC[jl][hc];
                const float p = sgn ? fmaxf(-v, 0.f) : fmaxf(v, 0.f);
                o[e] = (short)bfbits(p * woS[hc * NBINS + n]);
            }
            const int kc = (h0 >> 5) + sgn * 8;
            *(short8*)(Bp_f + ((size_t)(bb * 240 + rt0 + rtl) * NKP + kc) * 512 + l * 8) = o;
        }
    }
}

// ---------------- K2: out[b][i][jn] = A_f(i) . B'_f(jn) + bo[n]
// GEMM M=384,N=3840,K=512 per batch. Block 64i x 128jn, 4 waves,
// wave = 32i x 64jn (2 A-rt x 4 B-rt = 6 loads -> 8 MFMAs per ks).
// LDS-free, no barriers; all loads are coalesced 1KB frag bursts.
__global__ __launch_bounds__(256) void k2_pair(
    const short* __restrict__ A_f, const short* __restrict__ Bp_f,
    const float* __restrict__ bo, float* __restrict__ out)
{
    const int tid = threadIdx.x;
    const int lane = tid & 63, w = tid >> 6;
    const int iw = w & 1, jw = w >> 1;
    const int l15 = lane & 15, q = lane >> 4;
    const int b = blockIdx.z;
    const int i0 = blockIdx.x * 64, jn0 = blockIdx.y * 128;

    const short* ap = A_f + ((size_t)(b * 24 + (i0 >> 4) + iw * 2) * NKP) * 512 + lane * 8;
    const short* bp = Bp_f + ((size_t)(b * 240 + (jn0 >> 4) + jw * 4) * NKP) * 512 + lane * 8;

    float4v acc[2][4];
#pragma unroll
    for (int ia = 0; ia < 2; ++ia)
#pragma unroll
        for (int jb = 0; jb < 4; ++jb) acc[ia][jb] = (float4v){0.f, 0.f, 0.f, 0.f};

#pragma unroll 2
    for (int ks = 0; ks < NKP; ++ks) {
        const short8 af0 = *(const short8*)(ap + ks * 512);
        const short8 af1 = *(const short8*)(ap + (NKP + ks) * 512);
        short8 bf[4];
#pragma unroll
        for (int jb = 0; jb < 4; ++jb)
            bf[jb] = *(const short8*)(bp + ((size_t)jb * NKP + ks) * 512);
#pragma unroll
        for (int jb = 0; jb < 4; ++jb) {
            acc[0][jb] = __builtin_amdgcn_mfma_f32_16x16x32_bf16(af0, bf[jb], acc[0][jb], 0, 0, 0);
            acc[1][jb] = __builtin_amdgcn_mfma_f32_16x16x32_bf16(af1, bf[jb], acc[1][jb], 0, 0, 0);
        }
    }

    // epilogue: direct stores; C layout col=l15, row=q*4+r
#pragma unroll
    for (int jb = 0; jb < 4; ++jb) {
        const int jn = jn0 + jw * 64 + jb * 16 + l15;
        const int jq = (jn * 6554) >> 16;
        const int n = jn - jq * NBINS;
        const float bv = bo[n];
#pragma unroll
        for (int ia = 0; ia < 2; ++ia) {
            const int i = i0 + iw * 32 + ia * 16 + q * 4;
            float* orow = out + ((size_t)(b * LSEQ + i) * NJN) + jn;
#pragma unroll
            for (int r = 0; r < 4; ++r)
                orow[(size_t)r * NJN] = acc[ia][jb][r] + bv;
        }
    }
}

extern "C" void kernel_launch(void* const* d_in, const int* in_sizes, int n_in,
                              void* d_out, int out_size, void* d_ws, size_t ws_size,
                              hipStream_t stream)
{
    const float* x  = (const float*)d_in[0];
    const float* Wi = (const float*)d_in[1];
    const float* bi = (const float*)d_in[2];
    const float* Wj = (const float*)d_in[3];
    const float* bj = (const float*)d_in[4];
    const float* Wo = (const float*)d_in[5];
    const float* bo = (const float*)d_in[6];
    float* out = (float*)d_out;

    char* p = (char*)d_ws;
    short* xb_f = (short*)p;  p += (size_t)48 * NKX * 512 * 2;        // 1.97 MB
    short* WT_f = (short*)p;  p += (size_t)32 * NKX * 512 * 2;        // 1.31 MB
    short* A_f  = (short*)p;  p += (size_t)48 * NKP * 512 * 2;        // 0.79 MB
    short* Bp_f = (short*)p;                                           // 7.86 MB

    k_prep<<<1120, 256, 0, stream>>>(x, Wi, Wj, xb_f, WT_f);
    k_gemm_pack<<<dim3(GM / 32, 512 / 32), 256, 0, stream>>>(xb_f, WT_f, bi, bj, Wo, A_f, Bp_f);
    k2_pair<<<dim3(LSEQ / 64, NJN / 128, 2), 256, 0, stream>>>(A_f, Bp_f, bo, out);
}